// Round 1
// baseline (583.646 us; speedup 1.0000x reference)
//
#include <hip/hip_runtime.h>
#include <math.h>

#define NN 8192
#define CH 256

typedef unsigned long long u64;

// Pack (D value, index) into a single u64 whose unsigned ordering is
// lexicographic (D ascending, index ascending) — exactly lax.top_k's stable
// tie-break. Monotone float->uint map handles the (tiny) negative self-distance.
__device__ __forceinline__ u64 pack_di(float d, unsigned j) {
    unsigned u = __float_as_uint(d);
    u ^= (unsigned)((int)u >> 31) | 0x80000000u;
    return ((u64)u << 32) | (u64)j;
}

// Branchless sorted-insert of v into ascending triple (t0<=t1<=t2); largest drops.
__device__ __forceinline__ void ins3(u64 &t0, u64 &t1, u64 &t2, u64 v) {
    bool c0 = v < t0;
    u64 hi0 = c0 ? t0 : v;
    t0      = c0 ? v  : t0;
    bool c1 = hi0 < t1;
    u64 hi1 = c1 ? t1 : hi0;
    t1      = c1 ? hi0 : t1;
    t2      = hi1 < t2 ? hi1 : t2;
}

// ---------------- softmax + row sum-of-squares ----------------
// one wave per row; lane handles 4 contiguous floats
__global__ __launch_bounds__(256) void softmax_kernel(
    const float* __restrict__ x, float* __restrict__ p, float* __restrict__ sq)
{
    int wave = threadIdx.x >> 6, lane = threadIdx.x & 63;
    int row = blockIdx.x * 4 + wave;
    const float4* xr = (const float4*)(x + (size_t)row * CH);
    float4 v = xr[lane];
    float m = fmaxf(fmaxf(v.x, v.y), fmaxf(v.z, v.w));
    #pragma unroll
    for (int off = 32; off; off >>= 1) m = fmaxf(m, __shfl_xor(m, off, 64));
    float e0 = expf(v.x - m), e1 = expf(v.y - m), e2 = expf(v.z - m), e3 = expf(v.w - m);
    float s = (e0 + e1) + (e2 + e3);
    #pragma unroll
    for (int off = 32; off; off >>= 1) s += __shfl_xor(s, off, 64);
    float p0 = e0 / s, p1 = e1 / s, p2 = e2 / s, p3 = e3 / s;
    ((float4*)(p + (size_t)row * CH))[lane] = make_float4(p0, p1, p2, p3);
    float q = (p0 * p0 + p1 * p1) + (p2 * p2 + p3 * p3);
    #pragma unroll
    for (int off = 32; off; off >>= 1) q += __shfl_xor(q, off, 64);
    if (lane == 0) sq[row] = q;
}

// ---------------- generic f32 SGEMM: out = [relu]( A @ W^T [+bias] [+add] ) ----------------
// A: [M,K] row-major, W: [N,K] row-major. 64x64 tile, 256 threads, 4x4 micro.
template<bool RELU, bool HAS_BIAS, bool HAS_ADD>
__global__ __launch_bounds__(256) void gemm_nt(
    const float* __restrict__ A, const float* __restrict__ W,
    const float* __restrict__ bias, const float* __restrict__ add,
    float* __restrict__ out, int M, int N, int K)
{
    __shared__ float As[8][64];
    __shared__ float Ws[8][64];
    int tid = threadIdx.x;
    int tx = tid & 15, ty = tid >> 4;
    int mbase = blockIdx.x * 64, nbase = blockIdx.y * 64;
    int lrow = (tid & 127) >> 1;
    int lkoff = (tid & 1) * 4;
    const float* src = (tid < 128) ? (A + (size_t)(mbase + lrow) * K + lkoff)
                                   : (W + (size_t)(nbase + lrow) * K + lkoff);
    float* dst = (tid < 128) ? &As[0][0] : &Ws[0][0];
    float acc[4][4] = {};
    float4 v = *(const float4*)src;                 // prefetch panel 0
    for (int kk = 0; kk < K; kk += 8) {
        dst[(lkoff + 0) * 64 + lrow] = v.x;
        dst[(lkoff + 1) * 64 + lrow] = v.y;
        dst[(lkoff + 2) * 64 + lrow] = v.z;
        dst[(lkoff + 3) * 64 + lrow] = v.w;
        __syncthreads();
        if (kk + 8 < K) v = *(const float4*)(src + kk + 8);   // prefetch next panel
        #pragma unroll
        for (int k = 0; k < 8; ++k) {
            float4 a4 = *(const float4*)&As[k][ty * 4];
            float4 w4 = *(const float4*)&Ws[k][tx * 4];
            float ar[4] = {a4.x, a4.y, a4.z, a4.w};
            float wr[4] = {w4.x, w4.y, w4.z, w4.w};
            #pragma unroll
            for (int r = 0; r < 4; ++r)
                #pragma unroll
                for (int c = 0; c < 4; ++c)
                    acc[r][c] = fmaf(ar[r], wr[c], acc[r][c]);
        }
        __syncthreads();
    }
    float bv[4] = {0.f, 0.f, 0.f, 0.f};
    if (HAS_BIAS) {
        #pragma unroll
        for (int c = 0; c < 4; ++c) bv[c] = bias[nbase + tx * 4 + c];
    }
    #pragma unroll
    for (int r = 0; r < 4; ++r) {
        int row = mbase + ty * 4 + r;
        float o[4];
        #pragma unroll
        for (int c = 0; c < 4; ++c) {
            float val = acc[r][c];
            if (HAS_BIAS) val += bv[c];
            if (HAS_ADD) val += add[(size_t)row * N + nbase + tx * 4 + c];
            if (RELU) val = fmaxf(val, 0.0f);
            o[c] = val;
        }
        *(float4*)(out + (size_t)row * N + nbase + tx * 4) = make_float4(o[0], o[1], o[2], o[3]);
    }
}

// ---------------- pairwise-distance GEMM + per-(row, j-slice) top-3 ----------------
// 128x128 tile, 256 threads, 8x8 micro (split as 2x(4x4) for 2-way-free LDS reads).
// part layout: part[(i*64 + jtile)*3 + s]  (u64 packed (D,j))
__global__ __launch_bounds__(256) void dist_top3(
    const float* __restrict__ p, const float* __restrict__ sq, u64* __restrict__ part)
{
    __shared__ float As[8][128];
    __shared__ float Bs[8][128];
    int tid = threadIdx.x;
    int tx = tid & 15, ty = tid >> 4;
    int jt = blockIdx.x;
    int ibase = blockIdx.y * 128, jbase = jt * 128;
    int lrow = tid & 127;
    const float* src = p + (size_t)((tid < 128 ? ibase : jbase) + lrow) * CH;
    float* dst = (tid < 128) ? &As[0][0] : &Bs[0][0];
    float acc[8][8] = {};
    float4 v0 = *(const float4*)(src);
    float4 v1 = *(const float4*)(src + 4);
    for (int kk = 0; kk < CH; kk += 8) {
        dst[0 * 128 + lrow] = v0.x; dst[1 * 128 + lrow] = v0.y;
        dst[2 * 128 + lrow] = v0.z; dst[3 * 128 + lrow] = v0.w;
        dst[4 * 128 + lrow] = v1.x; dst[5 * 128 + lrow] = v1.y;
        dst[6 * 128 + lrow] = v1.z; dst[7 * 128 + lrow] = v1.w;
        __syncthreads();
        if (kk + 8 < CH) {
            v0 = *(const float4*)(src + kk + 8);
            v1 = *(const float4*)(src + kk + 12);
        }
        #pragma unroll
        for (int k = 0; k < 8; ++k) {
            float a[8], b[8];
            *(float4*)&a[0] = *(const float4*)&As[k][ty * 4];
            *(float4*)&a[4] = *(const float4*)&As[k][64 + ty * 4];
            *(float4*)&b[0] = *(const float4*)&Bs[k][tx * 4];
            *(float4*)&b[4] = *(const float4*)&Bs[k][64 + tx * 4];
            #pragma unroll
            for (int r = 0; r < 8; ++r)
                #pragma unroll
                for (int c = 0; c < 8; ++c)
                    acc[r][c] = fmaf(a[r], b[c], acc[r][c]);
        }
        __syncthreads();
    }
    // epilogue: D = (sq_i + sq_j) - 2*dot ; per-row top3 then 16-lane butterfly merge
    float sqi[8], sqj[8];
    #pragma unroll
    for (int r = 0; r < 8; ++r) {
        int gr = (r < 4) ? ty * 4 + r : 64 + ty * 4 + (r - 4);
        sqi[r] = sq[ibase + gr];
    }
    #pragma unroll
    for (int c = 0; c < 8; ++c) {
        int gc = (c < 4) ? tx * 4 + c : 64 + tx * 4 + (c - 4);
        sqj[c] = sq[jbase + gc];
    }
    #pragma unroll
    for (int r = 0; r < 8; ++r) {
        u64 t0 = ~0ULL, t1 = ~0ULL, t2 = ~0ULL;
        #pragma unroll
        for (int c = 0; c < 8; ++c) {
            int gc = (c < 4) ? tx * 4 + c : 64 + tx * 4 + (c - 4);
            float dv = (sqi[r] + sqj[c]) - 2.0f * acc[r][c];
            ins3(t0, t1, t2, pack_di(dv, (unsigned)(jbase + gc)));
        }
        // merge the 16 tx-thread triples of this row (lanes ty*16..ty*16+15)
        #pragma unroll
        for (int m = 1; m < 16; m <<= 1) {
            u64 b0 = __shfl_xor(t0, m, 64);
            u64 b1 = __shfl_xor(t1, m, 64);
            u64 b2 = __shfl_xor(t2, m, 64);
            ins3(t0, t1, t2, b0);
            ins3(t0, t1, t2, b1);
            ins3(t0, t1, t2, b2);
        }
        if (tx == 0) {
            int gr = (r < 4) ? ty * 4 + r : 64 + ty * 4 + (r - 4);
            u64* dp = part + ((size_t)(ibase + gr) * 64 + jt) * 3;
            dp[0] = t0; dp[1] = t1; dp[2] = t2;
        }
    }
}

// ---------------- merge 64 partial top-3s per row, gather+sum h rows ----------------
__global__ __launch_bounds__(256) void merge_gather(
    const u64* __restrict__ part, const float* __restrict__ h, float* __restrict__ agg)
{
    int wave = threadIdx.x >> 6, lane = threadIdx.x & 63;
    int row = blockIdx.x * 4 + wave;
    const u64* pr = part + (size_t)row * 192 + lane * 3;
    u64 t0 = pr[0], t1 = pr[1], t2 = pr[2];
    #pragma unroll
    for (int m = 32; m; m >>= 1) {
        u64 b0 = __shfl_xor(t0, m, 64);
        u64 b1 = __shfl_xor(t1, m, 64);
        u64 b2 = __shfl_xor(t2, m, 64);
        ins3(t0, t1, t2, b0);
        ins3(t0, t1, t2, b1);
        ins3(t0, t1, t2, b2);
    }
    int i0 = (int)(t0 & 0xffffffffu);
    int i1 = (int)(t1 & 0xffffffffu);
    int i2 = (int)(t2 & 0xffffffffu);
    const float4* h4 = (const float4*)h;
    float4 a = h4[(size_t)i0 * 64 + lane];
    float4 b = h4[(size_t)i1 * 64 + lane];
    float4 c = h4[(size_t)i2 * 64 + lane];
    float4 o;
    o.x = (a.x + b.x) + c.x;
    o.y = (a.y + b.y) + c.y;
    o.z = (a.z + b.z) + c.z;
    o.w = (a.w + b.w) + c.w;
    ((float4*)agg)[(size_t)row * 64 + lane] = o;
}

// ---------------- out = x1 @ W2^T + b2  (N=2) ----------------
__global__ __launch_bounds__(256) void linear2_kernel(
    const float* __restrict__ x1, const float* __restrict__ W2,
    const float* __restrict__ b2, float* __restrict__ out)
{
    int wave = threadIdx.x >> 6, lane = threadIdx.x & 63;
    int row = blockIdx.x * 4 + wave;
    float4 v = ((const float4*)(x1 + (size_t)row * CH))[lane];
    float4 w0 = ((const float4*)W2)[lane];
    float4 w1 = ((const float4*)W2)[64 + lane];
    float d0 = (v.x * w0.x + v.y * w0.y) + (v.z * w0.z + v.w * w0.w);
    float d1 = (v.x * w1.x + v.y * w1.y) + (v.z * w1.z + v.w * w1.w);
    #pragma unroll
    for (int off = 32; off; off >>= 1) {
        d0 += __shfl_xor(d0, off, 64);
        d1 += __shfl_xor(d1, off, 64);
    }
    if (lane == 0) {
        out[(size_t)row * 2 + 0] = d0 + b2[0];
        out[(size_t)row * 2 + 1] = d1 + b2[1];
    }
}

extern "C" void kernel_launch(void* const* d_in, const int* in_sizes, int n_in,
                              void* d_out, int out_size, void* d_ws, size_t ws_size,
                              hipStream_t stream) {
    const float* x    = (const float*)d_in[0];
    const float* W1   = (const float*)d_in[1];
    const float* b1   = (const float*)d_in[2];
    const float* Wrel = (const float*)d_in[3];
    const float* brel = (const float*)d_in[4];
    const float* Wroot= (const float*)d_in[5];
    const float* W2   = (const float*)d_in[6];
    const float* b2   = (const float*)d_in[7];

    float* outp = (float*)d_out;            // [8192*2] first
    float* x1   = outp + (size_t)NN * 2;    // [8192*256] second output

    char* ws = (char*)d_ws;
    const size_t SZ_MAT = (size_t)NN * CH * sizeof(float);     // 8 MB
    float* p    = (float*)(ws);                                 // 8 MB (reused as t later)
    float* h    = (float*)(ws + SZ_MAT);                        // 8 MB
    float* sq   = (float*)(ws + 2 * SZ_MAT);                    // 32 KB
    u64*   part = (u64*)  (ws + 2 * SZ_MAT + 65536);            // 8192*64*3*8 = 12 MB
    float* agg  = (float*)(ws + 2 * SZ_MAT + 65536 + (size_t)NN * 64 * 3 * 8);  // 8 MB
    float* t    = p;   // p is dead after dist_top3; reuse for (agg@Wrel^T + brel)

    // 1. softmax + sq
    softmax_kernel<<<NN / 4, 256, 0, stream>>>(x, p, sq);
    // 2. h = relu(x @ W1^T + b1)
    gemm_nt<true, true, false><<<dim3(NN / 64, CH / 64), 256, 0, stream>>>(
        x, W1, b1, nullptr, h, NN, CH, CH);
    // 3. pairwise distances + per-slice top3
    dist_top3<<<dim3(64, 64), 256, 0, stream>>>(p, sq, part);
    // 4. global top3 merge + gather-sum of h rows
    merge_gather<<<NN / 4, 256, 0, stream>>>(part, h, agg);
    // 5. t = agg @ Wrel^T + brel
    gemm_nt<false, true, false><<<dim3(NN / 64, CH / 64), 256, 0, stream>>>(
        agg, Wrel, brel, nullptr, t, NN, CH, CH);
    // 6. x1 = relu(h @ Wroot^T + t)   -> second output region
    gemm_nt<true, false, true><<<dim3(NN / 64, CH / 64), 256, 0, stream>>>(
        h, Wroot, nullptr, t, x1, NN, CH, CH);
    // 7. out = x1 @ W2^T + b2
    linear2_kernel<<<NN / 4, 256, 0, stream>>>(x1, W2, b2, outp);
}

// Round 2
// 421.613 us; speedup vs baseline: 1.3843x; 1.3843x over previous
//
#include <hip/hip_runtime.h>
#include <hip/hip_bf16.h>
#include <math.h>

#define NN 8192
#define CH 256

typedef unsigned long long u64;
typedef __attribute__((ext_vector_type(8))) short s16x8;
typedef __attribute__((ext_vector_type(4))) float f32x4;

// Pack (D value, index) into a single u64 whose unsigned ordering is
// lexicographic (D ascending, index ascending) — exactly lax.top_k's stable
// tie-break. Monotone float->uint map handles the (tiny) negative self-distance.
__device__ __forceinline__ u64 pack_di(float d, unsigned j) {
    unsigned u = __float_as_uint(d);
    u ^= (unsigned)((int)u >> 31) | 0x80000000u;
    return ((u64)u << 32) | (u64)j;
}

// Branchless sorted-insert of v into ascending triple (t0<=t1<=t2); largest drops.
__device__ __forceinline__ void ins3(u64 &t0, u64 &t1, u64 &t2, u64 v) {
    bool c0 = v < t0;
    u64 hi0 = c0 ? t0 : v;
    t0      = c0 ? v  : t0;
    bool c1 = hi0 < t1;
    u64 hi1 = c1 ? t1 : hi0;
    t1      = c1 ? hi0 : t1;
    t2      = hi1 < t2 ? hi1 : t2;
}

// async global->LDS, 16B per lane, dest = base + lane*16
__device__ __forceinline__ void gl_lds16(const void* g, void* l) {
    __builtin_amdgcn_global_load_lds(
        (const __attribute__((address_space(1))) unsigned int*)g,
        (__attribute__((address_space(3))) unsigned int*)l, 16, 0, 0);
}

// ---------------- softmax + row sum-of-squares ----------------
__global__ __launch_bounds__(256) void softmax_kernel(
    const float* __restrict__ x, float* __restrict__ p, float* __restrict__ sq)
{
    int wave = threadIdx.x >> 6, lane = threadIdx.x & 63;
    int row = blockIdx.x * 4 + wave;
    const float4* xr = (const float4*)(x + (size_t)row * CH);
    float4 v = xr[lane];
    float m = fmaxf(fmaxf(v.x, v.y), fmaxf(v.z, v.w));
    #pragma unroll
    for (int off = 32; off; off >>= 1) m = fmaxf(m, __shfl_xor(m, off, 64));
    float e0 = expf(v.x - m), e1 = expf(v.y - m), e2 = expf(v.z - m), e3 = expf(v.w - m);
    float s = (e0 + e1) + (e2 + e3);
    #pragma unroll
    for (int off = 32; off; off >>= 1) s += __shfl_xor(s, off, 64);
    float p0 = e0 / s, p1 = e1 / s, p2 = e2 / s, p3 = e3 / s;
    ((float4*)(p + (size_t)row * CH))[lane] = make_float4(p0, p1, p2, p3);
    float q = (p0 * p0 + p1 * p1) + (p2 * p2 + p3 * p3);
    #pragma unroll
    for (int off = 32; off; off >>= 1) q += __shfl_xor(q, off, 64);
    if (lane == 0) sq[row] = q;
}

// ---------------- split f32 -> bf16 hi/mid/lo ----------------
__device__ __forceinline__ void split1(float a, unsigned short& h, unsigned short& m, unsigned short& l) {
    __hip_bfloat16 bh = __float2bfloat16(a);
    float fh = __bfloat162float(bh);
    float r = a - fh;
    __hip_bfloat16 bm = __float2bfloat16(r);
    float fm = __bfloat162float(bm);
    __hip_bfloat16 bl = __float2bfloat16(r - fm);
    h = *(unsigned short*)&bh; m = *(unsigned short*)&bm; l = *(unsigned short*)&bl;
}

__global__ __launch_bounds__(256) void split3_kernel(
    const float* __restrict__ p, unsigned short* __restrict__ pa,
    unsigned short* __restrict__ pb, unsigned short* __restrict__ pc)
{
    int i = blockIdx.x * 1024 + threadIdx.x * 4;
    float4 v = *(const float4*)(p + i);
    ushort4 H, M, L;
    split1(v.x, H.x, M.x, L.x);
    split1(v.y, H.y, M.y, L.y);
    split1(v.z, H.z, M.z, L.z);
    split1(v.w, H.w, M.w, L.w);
    *(ushort4*)(pa + i) = H;
    *(ushort4*)(pb + i) = M;
    *(ushort4*)(pc + i) = L;
}

// ---------------- generic f32 SGEMM: out = [relu]( A @ W^T [+bias] [+add] ) ----------------
template<bool RELU, bool HAS_BIAS, bool HAS_ADD>
__global__ __launch_bounds__(256) void gemm_nt(
    const float* __restrict__ A, const float* __restrict__ W,
    const float* __restrict__ bias, const float* __restrict__ add,
    float* __restrict__ out, int M, int N, int K)
{
    __shared__ float As[8][64];
    __shared__ float Ws[8][64];
    int tid = threadIdx.x;
    int tx = tid & 15, ty = tid >> 4;
    int mbase = blockIdx.x * 64, nbase = blockIdx.y * 64;
    int lrow = (tid & 127) >> 1;
    int lkoff = (tid & 1) * 4;
    const float* src = (tid < 128) ? (A + (size_t)(mbase + lrow) * K + lkoff)
                                   : (W + (size_t)(nbase + lrow) * K + lkoff);
    float* dst = (tid < 128) ? &As[0][0] : &Ws[0][0];
    float acc[4][4] = {};
    float4 v = *(const float4*)src;
    for (int kk = 0; kk < K; kk += 8) {
        dst[(lkoff + 0) * 64 + lrow] = v.x;
        dst[(lkoff + 1) * 64 + lrow] = v.y;
        dst[(lkoff + 2) * 64 + lrow] = v.z;
        dst[(lkoff + 3) * 64 + lrow] = v.w;
        __syncthreads();
        if (kk + 8 < K) v = *(const float4*)(src + kk + 8);
        #pragma unroll
        for (int k = 0; k < 8; ++k) {
            float4 a4 = *(const float4*)&As[k][ty * 4];
            float4 w4 = *(const float4*)&Ws[k][tx * 4];
            float ar[4] = {a4.x, a4.y, a4.z, a4.w};
            float wr[4] = {w4.x, w4.y, w4.z, w4.w};
            #pragma unroll
            for (int r = 0; r < 4; ++r)
                #pragma unroll
                for (int c = 0; c < 4; ++c)
                    acc[r][c] = fmaf(ar[r], wr[c], acc[r][c]);
        }
        __syncthreads();
    }
    float bv[4] = {0.f, 0.f, 0.f, 0.f};
    if (HAS_BIAS) {
        #pragma unroll
        for (int c = 0; c < 4; ++c) bv[c] = bias[nbase + tx * 4 + c];
    }
    #pragma unroll
    for (int r = 0; r < 4; ++r) {
        int row = mbase + ty * 4 + r;
        float o[4];
        #pragma unroll
        for (int c = 0; c < 4; ++c) {
            float val = acc[r][c];
            if (HAS_BIAS) val += bv[c];
            if (HAS_ADD) val += add[(size_t)row * N + nbase + tx * 4 + c];
            if (RELU) val = fmaxf(val, 0.0f);
            o[c] = val;
        }
        *(float4*)(out + (size_t)row * N + nbase + tx * 4) = make_float4(o[0], o[1], o[2], o[3]);
    }
}

// ---------------- pairwise-distance via split-bf16 MFMA + per-(row,128-col-slice) top-3 ----
// 128x128 tile, 4 waves in 2x2. BK=32 (one 16x16x32 MFMA K-step).
// dot = aH*bH + aH*bM + aM*bH + aM*bM + aH*bL + aL*bH  (f32 acc, err ~2^-32 rel)
// part layout: part[(i*64 + jtile)*3 + s]  (u64 packed (D,j))
__global__ __launch_bounds__(256, 2) void dist_top3_mfma(
    const unsigned short* __restrict__ pa, const unsigned short* __restrict__ pb,
    const unsigned short* __restrict__ pc, const float* __restrict__ sq,
    u64* __restrict__ part)
{
    __shared__ short sA[3][128 * 32];
    __shared__ short sB[3][128 * 32];
    __shared__ u64 xbuf[128][3];

    int tid = threadIdx.x;
    int wave = tid >> 6, lane = tid & 63;
    int wi = wave >> 1, wj = wave & 1;
    int lc = lane & 15, q = lane >> 4;
    int jt = blockIdx.x;
    int ibase = blockIdx.y * 128, jbase = jt * 128;

    f32x4 acc[4][4];
    #pragma unroll
    for (int mt = 0; mt < 4; ++mt)
        #pragma unroll
        for (int nt = 0; nt < 4; ++nt)
            acc[mt][nt] = (f32x4){0.f, 0.f, 0.f, 0.f};

    int srow = lane >> 2;             // staging: lane -> row-in-chunk
    int skq  = (lane & 3) * 8;        // staging: lane -> k offset (8 bf16 = 16B)

    for (int kk = 0; kk < CH; kk += 32) {
        // ---- stage A/B tiles for all 3 components (wave w stages chunks 2w,2w+1) ----
        #pragma unroll
        for (int c = 0; c < 3; ++c) {
            const unsigned short* gp = (c == 0) ? pa : (c == 1) ? pb : pc;
            #pragma unroll
            for (int ch = 0; ch < 2; ++ch) {
                int r0 = (wave * 2 + ch) * 16;
                gl_lds16(gp + (size_t)(ibase + r0 + srow) * CH + kk + skq, &sA[c][r0 * 32]);
                gl_lds16(gp + (size_t)(jbase + r0 + srow) * CH + kk + skq, &sB[c][r0 * 32]);
            }
        }
        __syncthreads();

        // ---- fragments + 6 MFMA products ----
        s16x8 aH[4], bH[4], aM[4], bM[4], aL[4], bL[4];
        #pragma unroll
        for (int mt = 0; mt < 4; ++mt)
            aH[mt] = *(const s16x8*)&sA[0][(wi * 64 + mt * 16 + lc) * 32 + q * 8];
        #pragma unroll
        for (int nt = 0; nt < 4; ++nt)
            bH[nt] = *(const s16x8*)&sB[0][(wj * 64 + nt * 16 + lc) * 32 + q * 8];
        #pragma unroll
        for (int mt = 0; mt < 4; ++mt)
            #pragma unroll
            for (int nt = 0; nt < 4; ++nt)
                acc[mt][nt] = __builtin_amdgcn_mfma_f32_16x16x32_bf16(aH[mt], bH[nt], acc[mt][nt], 0, 0, 0);

        #pragma unroll
        for (int nt = 0; nt < 4; ++nt)
            bM[nt] = *(const s16x8*)&sB[1][(wj * 64 + nt * 16 + lc) * 32 + q * 8];
        #pragma unroll
        for (int mt = 0; mt < 4; ++mt)
            #pragma unroll
            for (int nt = 0; nt < 4; ++nt)
                acc[mt][nt] = __builtin_amdgcn_mfma_f32_16x16x32_bf16(aH[mt], bM[nt], acc[mt][nt], 0, 0, 0);

        #pragma unroll
        for (int mt = 0; mt < 4; ++mt)
            aM[mt] = *(const s16x8*)&sA[1][(wi * 64 + mt * 16 + lc) * 32 + q * 8];
        #pragma unroll
        for (int mt = 0; mt < 4; ++mt)
            #pragma unroll
            for (int nt = 0; nt < 4; ++nt)
                acc[mt][nt] = __builtin_amdgcn_mfma_f32_16x16x32_bf16(aM[mt], bH[nt], acc[mt][nt], 0, 0, 0);
        #pragma unroll
        for (int mt = 0; mt < 4; ++mt)
            #pragma unroll
            for (int nt = 0; nt < 4; ++nt)
                acc[mt][nt] = __builtin_amdgcn_mfma_f32_16x16x32_bf16(aM[mt], bM[nt], acc[mt][nt], 0, 0, 0);

        #pragma unroll
        for (int nt = 0; nt < 4; ++nt)
            bL[nt] = *(const s16x8*)&sB[2][(wj * 64 + nt * 16 + lc) * 32 + q * 8];
        #pragma unroll
        for (int mt = 0; mt < 4; ++mt)
            #pragma unroll
            for (int nt = 0; nt < 4; ++nt)
                acc[mt][nt] = __builtin_amdgcn_mfma_f32_16x16x32_bf16(aH[mt], bL[nt], acc[mt][nt], 0, 0, 0);

        #pragma unroll
        for (int mt = 0; mt < 4; ++mt)
            aL[mt] = *(const s16x8*)&sA[2][(wi * 64 + mt * 16 + lc) * 32 + q * 8];
        #pragma unroll
        for (int mt = 0; mt < 4; ++mt)
            #pragma unroll
            for (int nt = 0; nt < 4; ++nt)
                acc[mt][nt] = __builtin_amdgcn_mfma_f32_16x16x32_bf16(aL[mt], bH[nt], acc[mt][nt], 0, 0, 0);

        __syncthreads();
    }

    // ---- epilogue: D = (sq_i + sq_j) - 2*dot, per-row top3, merge across lanes/waves ----
    float sqjv[4];
    #pragma unroll
    for (int nt = 0; nt < 4; ++nt) sqjv[nt] = sq[jbase + wj * 64 + nt * 16 + lc];

    #pragma unroll
    for (int mt = 0; mt < 4; ++mt) {
        u64 trip[4][3];
        #pragma unroll
        for (int rg = 0; rg < 4; ++rg) {
            int rl = mt * 16 + q * 4 + rg;                 // row within wave's 64-row half
            float sqi = sq[ibase + wi * 64 + rl];
            u64 t0 = ~0ULL, t1 = ~0ULL, t2 = ~0ULL;
            #pragma unroll
            for (int nt = 0; nt < 4; ++nt) {
                float dv = (sqi + sqjv[nt]) - 2.0f * acc[mt][nt][rg];
                unsigned col = (unsigned)(jbase + wj * 64 + nt * 16 + lc);
                ins3(t0, t1, t2, pack_di(dv, col));
            }
            #pragma unroll
            for (int m = 1; m < 16; m <<= 1) {
                u64 b0 = __shfl_xor(t0, m, 64);
                u64 b1 = __shfl_xor(t1, m, 64);
                u64 b2 = __shfl_xor(t2, m, 64);
                ins3(t0, t1, t2, b0);
                ins3(t0, t1, t2, b1);
                ins3(t0, t1, t2, b2);
            }
            trip[rg][0] = t0; trip[rg][1] = t1; trip[rg][2] = t2;
        }
        int rbase = wi * 64 + mt * 16 + q * 4;
        if (wj == 1 && lc == 0) {
            #pragma unroll
            for (int rg = 0; rg < 4; ++rg) {
                xbuf[rbase + rg][0] = trip[rg][0];
                xbuf[rbase + rg][1] = trip[rg][1];
                xbuf[rbase + rg][2] = trip[rg][2];
            }
        }
        __syncthreads();
        if (wj == 0 && lc == 0) {
            #pragma unroll
            for (int rg = 0; rg < 4; ++rg) {
                u64 t0 = trip[rg][0], t1 = trip[rg][1], t2 = trip[rg][2];
                ins3(t0, t1, t2, xbuf[rbase + rg][0]);
                ins3(t0, t1, t2, xbuf[rbase + rg][1]);
                ins3(t0, t1, t2, xbuf[rbase + rg][2]);
                u64* dp = part + ((size_t)(ibase + rbase + rg) * 64 + jt) * 3;
                dp[0] = t0; dp[1] = t1; dp[2] = t2;
            }
        }
        __syncthreads();
    }
}

// ---------------- merge 64 partial top-3s per row, gather+sum h rows ----------------
__global__ __launch_bounds__(256) void merge_gather(
    const u64* __restrict__ part, const float* __restrict__ h, float* __restrict__ agg)
{
    int wave = threadIdx.x >> 6, lane = threadIdx.x & 63;
    int row = blockIdx.x * 4 + wave;
    const u64* pr = part + (size_t)row * 192 + lane * 3;
    u64 t0 = pr[0], t1 = pr[1], t2 = pr[2];
    #pragma unroll
    for (int m = 32; m; m >>= 1) {
        u64 b0 = __shfl_xor(t0, m, 64);
        u64 b1 = __shfl_xor(t1, m, 64);
        u64 b2 = __shfl_xor(t2, m, 64);
        ins3(t0, t1, t2, b0);
        ins3(t0, t1, t2, b1);
        ins3(t0, t1, t2, b2);
    }
    int i0 = (int)(t0 & 0xffffffffu);
    int i1 = (int)(t1 & 0xffffffffu);
    int i2 = (int)(t2 & 0xffffffffu);
    const float4* h4 = (const float4*)h;
    float4 a = h4[(size_t)i0 * 64 + lane];
    float4 b = h4[(size_t)i1 * 64 + lane];
    float4 c = h4[(size_t)i2 * 64 + lane];
    float4 o;
    o.x = (a.x + b.x) + c.x;
    o.y = (a.y + b.y) + c.y;
    o.z = (a.z + b.z) + c.z;
    o.w = (a.w + b.w) + c.w;
    ((float4*)agg)[(size_t)row * 64 + lane] = o;
}

// ---------------- out = x1 @ W2^T + b2  (N=2) ----------------
__global__ __launch_bounds__(256) void linear2_kernel(
    const float* __restrict__ x1, const float* __restrict__ W2,
    const float* __restrict__ b2, float* __restrict__ out)
{
    int wave = threadIdx.x >> 6, lane = threadIdx.x & 63;
    int row = blockIdx.x * 4 + wave;
    float4 v = ((const float4*)(x1 + (size_t)row * CH))[lane];
    float4 w0 = ((const float4*)W2)[lane];
    float4 w1 = ((const float4*)W2)[64 + lane];
    float d0 = (v.x * w0.x + v.y * w0.y) + (v.z * w0.z + v.w * w0.w);
    float d1 = (v.x * w1.x + v.y * w1.y) + (v.z * w1.z + v.w * w1.w);
    #pragma unroll
    for (int off = 32; off; off >>= 1) {
        d0 += __shfl_xor(d0, off, 64);
        d1 += __shfl_xor(d1, off, 64);
    }
    if (lane == 0) {
        out[(size_t)row * 2 + 0] = d0 + b2[0];
        out[(size_t)row * 2 + 1] = d1 + b2[1];
    }
}

extern "C" void kernel_launch(void* const* d_in, const int* in_sizes, int n_in,
                              void* d_out, int out_size, void* d_ws, size_t ws_size,
                              hipStream_t stream) {
    const float* x    = (const float*)d_in[0];
    const float* W1   = (const float*)d_in[1];
    const float* b1   = (const float*)d_in[2];
    const float* Wrel = (const float*)d_in[3];
    const float* brel = (const float*)d_in[4];
    const float* Wroot= (const float*)d_in[5];
    const float* W2   = (const float*)d_in[6];
    const float* b2   = (const float*)d_in[7];

    float* outp = (float*)d_out;            // [8192*2] first
    float* x1   = outp + (size_t)NN * 2;    // [8192*256] second output

    char* ws = (char*)d_ws;
    float* p   = (float*)ws;                                   // 8 MB (reused as agg)
    float* h   = (float*)(ws + (size_t)(8u << 20));            // 8 MB
    float* sq  = (float*)(ws + (size_t)(16u << 20));           // 32 KB
    char*  sp  = ws + (size_t)(16u << 20) + (64u << 10);
    unsigned short* pa = (unsigned short*)sp;                  // 4 MB (reused as t)
    unsigned short* pb = (unsigned short*)(sp + (size_t)(4u << 20));
    unsigned short* pc = (unsigned short*)(sp + (size_t)(8u << 20));
    u64* part = (u64*)(sp + (size_t)(12u << 20));              // 12 MB
    float* agg = p;    // p dead after split3/dist
    float* t   = (float*)pa;  // pa dead after dist

    // 1. softmax + sq
    softmax_kernel<<<NN / 4, 256, 0, stream>>>(x, p, sq);
    // 2. split p into bf16 hi/mid/lo
    split3_kernel<<<(NN * CH) / 1024, 256, 0, stream>>>(p, pa, pb, pc);
    // 3. h = relu(x @ W1^T + b1)
    gemm_nt<true, true, false><<<dim3(NN / 64, CH / 64), 256, 0, stream>>>(
        x, W1, b1, nullptr, h, NN, CH, CH);
    // 4. pairwise distances via split-bf16 MFMA + per-slice top3
    dist_top3_mfma<<<dim3(64, 64), 256, 0, stream>>>(pa, pb, pc, sq, part);
    // 5. global top3 merge + gather-sum of h rows
    merge_gather<<<NN / 4, 256, 0, stream>>>(part, h, agg);
    // 6. t = agg @ Wrel^T + brel
    gemm_nt<false, true, false><<<dim3(NN / 64, CH / 64), 256, 0, stream>>>(
        agg, Wrel, brel, nullptr, t, NN, CH, CH);
    // 7. x1 = relu(h @ Wroot^T + t)   -> second output region
    gemm_nt<true, false, true><<<dim3(NN / 64, CH / 64), 256, 0, stream>>>(
        h, Wroot, nullptr, t, x1, NN, CH, CH);
    // 8. out = x1 @ W2^T + b2
    linear2_kernel<<<NN / 4, 256, 0, stream>>>(x1, W2, b2, outp);
}

// Round 3
// 344.666 us; speedup vs baseline: 1.6934x; 1.2233x over previous
//
#include <hip/hip_runtime.h>
#include <hip/hip_bf16.h>
#include <math.h>

#define NN 8192
#define CH 256

typedef unsigned long long u64;
typedef __attribute__((ext_vector_type(8))) short s16x8;
typedef __attribute__((ext_vector_type(4))) float f32x4;

// Pack (D value, index) into a single u64 whose unsigned ordering is
// lexicographic (D ascending, index ascending) — exactly lax.top_k's stable
// tie-break. Monotone float->uint map handles the (tiny) negative self-distance.
__device__ __forceinline__ u64 pack_di(float d, unsigned j) {
    unsigned u = __float_as_uint(d);
    u ^= (unsigned)((int)u >> 31) | 0x80000000u;
    return ((u64)u << 32) | (u64)j;
}

// Branchless sorted-insert of v into ascending triple (t0<=t1<=t2); largest drops.
__device__ __forceinline__ void ins3(u64 &t0, u64 &t1, u64 &t2, u64 v) {
    bool c0 = v < t0;
    u64 hi0 = c0 ? t0 : v;
    t0      = c0 ? v  : t0;
    bool c1 = hi0 < t1;
    u64 hi1 = c1 ? t1 : hi0;
    t1      = c1 ? hi0 : t1;
    t2      = hi1 < t2 ? hi1 : t2;
}

__device__ __forceinline__ u64 umin64(u64 a, u64 b) { return a < b ? a : b; }
__device__ __forceinline__ u64 umax64(u64 a, u64 b) { return a < b ? b : a; }

// Merge two ascending triples -> ascending top-3 of the union (merge network,
// ~19 instrs vs 36 for 3x ins3).
__device__ __forceinline__ void merge3(u64 &a0, u64 &a1, u64 &a2, u64 b0, u64 b1, u64 b2) {
    u64 m0 = umin64(a0, b0), M0 = umax64(a0, b0);
    u64 m1 = umin64(a1, b1);
    u64 m2 = umin64(a2, b2);
    u64 s  = umin64(M0, m1), S = umax64(M0, m1);
    a0 = m0;
    a1 = s;
    a2 = umin64(S, m2);
}

// async global->LDS, 16B per lane, dest = wave-uniform base + lane*16
__device__ __forceinline__ void gl_lds16(const void* g, void* l) {
    __builtin_amdgcn_global_load_lds(
        (const __attribute__((address_space(1))) unsigned int*)g,
        (__attribute__((address_space(3))) unsigned int*)l, 16, 0, 0);
}

// ---------------- softmax + row sum-of-squares ----------------
__global__ __launch_bounds__(256) void softmax_kernel(
    const float* __restrict__ x, float* __restrict__ p, float* __restrict__ sq)
{
    int wave = threadIdx.x >> 6, lane = threadIdx.x & 63;
    int row = blockIdx.x * 4 + wave;
    const float4* xr = (const float4*)(x + (size_t)row * CH);
    float4 v = xr[lane];
    float m = fmaxf(fmaxf(v.x, v.y), fmaxf(v.z, v.w));
    #pragma unroll
    for (int off = 32; off; off >>= 1) m = fmaxf(m, __shfl_xor(m, off, 64));
    float e0 = expf(v.x - m), e1 = expf(v.y - m), e2 = expf(v.z - m), e3 = expf(v.w - m);
    float s = (e0 + e1) + (e2 + e3);
    #pragma unroll
    for (int off = 32; off; off >>= 1) s += __shfl_xor(s, off, 64);
    float p0 = e0 / s, p1 = e1 / s, p2 = e2 / s, p3 = e3 / s;
    ((float4*)(p + (size_t)row * CH))[lane] = make_float4(p0, p1, p2, p3);
    float q = (p0 * p0 + p1 * p1) + (p2 * p2 + p3 * p3);
    #pragma unroll
    for (int off = 32; off; off >>= 1) q += __shfl_xor(q, off, 64);
    if (lane == 0) sq[row] = q;
}

// ---------------- splits ----------------
__device__ __forceinline__ void split1(float a, unsigned short& h, unsigned short& m, unsigned short& l) {
    __hip_bfloat16 bh = __float2bfloat16(a);
    float fh = __bfloat162float(bh);
    float r = a - fh;
    __hip_bfloat16 bm = __float2bfloat16(r);
    float fm = __bfloat162float(bm);
    __hip_bfloat16 bl = __float2bfloat16(r - fm);
    h = *(unsigned short*)&bh; m = *(unsigned short*)&bm; l = *(unsigned short*)&bl;
}

__device__ __forceinline__ void split2one(float a, unsigned short& h, unsigned short& m) {
    __hip_bfloat16 bh = __float2bfloat16(a);
    float r = a - __bfloat162float(bh);
    __hip_bfloat16 bm = __float2bfloat16(r);
    h = *(unsigned short*)&bh; m = *(unsigned short*)&bm;
}

__global__ __launch_bounds__(256) void split3_kernel(
    const float* __restrict__ p, unsigned short* __restrict__ pa,
    unsigned short* __restrict__ pb, unsigned short* __restrict__ pc)
{
    int i = blockIdx.x * 1024 + threadIdx.x * 4;
    float4 v = *(const float4*)(p + i);
    ushort4 H, M, L;
    split1(v.x, H.x, M.x, L.x);
    split1(v.y, H.y, M.y, L.y);
    split1(v.z, H.z, M.z, L.z);
    split1(v.w, H.w, M.w, L.w);
    *(ushort4*)(pa + i) = H;
    *(ushort4*)(pb + i) = M;
    *(ushort4*)(pc + i) = L;
}

__global__ __launch_bounds__(256) void split2_kernel(
    const float* __restrict__ src, unsigned short* __restrict__ dh,
    unsigned short* __restrict__ dm)
{
    int i = blockIdx.x * 1024 + threadIdx.x * 4;
    float4 v = *(const float4*)(src + i);
    ushort4 H, M;
    split2one(v.x, H.x, M.x);
    split2one(v.y, H.y, M.y);
    split2one(v.z, H.z, M.z);
    split2one(v.w, H.w, M.w);
    *(ushort4*)(dh + i) = H;
    *(ushort4*)(dm + i) = M;
}

// split 3 weight matrices (256x256 each) in one launch: blocks [0,64)->W1, [64,128)->Wrel, [128,192)->Wroot
__global__ __launch_bounds__(256) void splitw_kernel(
    const float* __restrict__ s0, const float* __restrict__ s1, const float* __restrict__ s2,
    unsigned short* __restrict__ d0h, unsigned short* __restrict__ d0m,
    unsigned short* __restrict__ d1h, unsigned short* __restrict__ d1m,
    unsigned short* __restrict__ d2h, unsigned short* __restrict__ d2m)
{
    int which = blockIdx.x >> 6;
    const float* s = (which == 0) ? s0 : (which == 1) ? s1 : s2;
    unsigned short* dh = (which == 0) ? d0h : (which == 1) ? d1h : d2h;
    unsigned short* dm = (which == 0) ? d0m : (which == 1) ? d1m : d2m;
    int i = (blockIdx.x & 63) * 1024 + threadIdx.x * 4;
    float4 v = *(const float4*)(s + i);
    ushort4 H, M;
    split2one(v.x, H.x, M.x);
    split2one(v.y, H.y, M.y);
    split2one(v.z, H.z, M.z);
    split2one(v.w, H.w, M.w);
    *(ushort4*)(dh + i) = H;
    *(ushort4*)(dm + i) = M;
}

// ---------------- split-2 bf16 MFMA GEMM: out = [relu](A @ W^T [+bias] [+add]) --------
// A: [M,256] f32 pre-split into (Ah,Am); W: [256,256] pre-split. out: [M,256] f32.
// 128(M) x 64(N) tile, 4 waves; wave w owns rows w*32..w*32+31, all 64 cols.
// dot = aH*bH + aH*bM + aM*bH  (rel err ~2^-16, vs 0.057 output tolerance).
template<bool RELU, bool HAS_BIAS, bool HAS_ADD>
__global__ __launch_bounds__(256, 2) void gemm_mfma(
    const unsigned short* __restrict__ Ah, const unsigned short* __restrict__ Am,
    const unsigned short* __restrict__ Wh, const unsigned short* __restrict__ Wm,
    const float* __restrict__ bias, const float* __restrict__ add,
    float* __restrict__ out)
{
    __shared__ short sAh[128 * 32], sAm[128 * 32], sBh[64 * 32], sBm[64 * 32];
    int tid = threadIdx.x;
    int wave = tid >> 6, lane = tid & 63;
    int lc = lane & 15, q = lane >> 4;
    int mbase = blockIdx.x * 128, nbase = blockIdx.y * 64;

    f32x4 acc[2][4];
    #pragma unroll
    for (int mt = 0; mt < 2; ++mt)
        #pragma unroll
        for (int nt = 0; nt < 4; ++nt)
            acc[mt][nt] = (f32x4){0.f, 0.f, 0.f, 0.f};

    int srow = lane >> 2;
    int skq  = ((lane & 3) ^ ((lane >> 3) & 3)) * 8;   // XOR-swizzled global 16B slot

    const unsigned short* gsrc[6];
    short* ldst[6];
    {
        int rA0 = wave * 32;
        gsrc[0] = Ah + (size_t)(mbase + rA0 + srow) * CH + skq;      ldst[0] = &sAh[rA0 * 32];
        gsrc[1] = Ah + (size_t)(mbase + rA0 + 16 + srow) * CH + skq; ldst[1] = &sAh[(rA0 + 16) * 32];
        gsrc[2] = Am + (size_t)(mbase + rA0 + srow) * CH + skq;      ldst[2] = &sAm[rA0 * 32];
        gsrc[3] = Am + (size_t)(mbase + rA0 + 16 + srow) * CH + skq; ldst[3] = &sAm[(rA0 + 16) * 32];
        const unsigned short* Bsrc = (wave >> 1) ? Wm : Wh;
        short* Bdst = (wave >> 1) ? sBm : sBh;
        int rB0 = (wave & 1) * 32;
        gsrc[4] = Bsrc + (size_t)(nbase + rB0 + srow) * CH + skq;      ldst[4] = Bdst + rB0 * 32;
        gsrc[5] = Bsrc + (size_t)(nbase + rB0 + 16 + srow) * CH + skq; ldst[5] = Bdst + (rB0 + 16) * 32;
    }
    int cq = (q ^ ((lc >> 1) & 3)) * 8;               // swizzled LDS slot for frag reads

    for (int kk = 0; kk < CH; kk += 32) {
        #pragma unroll
        for (int t = 0; t < 6; ++t) { gl_lds16(gsrc[t], ldst[t]); gsrc[t] += 32; }
        __syncthreads();
        s16x8 aH[2], aM[2], bH[4], bM[4];
        #pragma unroll
        for (int mt = 0; mt < 2; ++mt) {
            aH[mt] = *(const s16x8*)&sAh[(wave * 32 + mt * 16 + lc) * 32 + cq];
            aM[mt] = *(const s16x8*)&sAm[(wave * 32 + mt * 16 + lc) * 32 + cq];
        }
        #pragma unroll
        for (int nt = 0; nt < 4; ++nt) {
            bH[nt] = *(const s16x8*)&sBh[(nt * 16 + lc) * 32 + cq];
            bM[nt] = *(const s16x8*)&sBm[(nt * 16 + lc) * 32 + cq];
        }
        #pragma unroll
        for (int mt = 0; mt < 2; ++mt)
            #pragma unroll
            for (int nt = 0; nt < 4; ++nt)
                acc[mt][nt] = __builtin_amdgcn_mfma_f32_16x16x32_bf16(aH[mt], bH[nt], acc[mt][nt], 0, 0, 0);
        #pragma unroll
        for (int mt = 0; mt < 2; ++mt)
            #pragma unroll
            for (int nt = 0; nt < 4; ++nt)
                acc[mt][nt] = __builtin_amdgcn_mfma_f32_16x16x32_bf16(aH[mt], bM[nt], acc[mt][nt], 0, 0, 0);
        #pragma unroll
        for (int mt = 0; mt < 2; ++mt)
            #pragma unroll
            for (int nt = 0; nt < 4; ++nt)
                acc[mt][nt] = __builtin_amdgcn_mfma_f32_16x16x32_bf16(aM[mt], bH[nt], acc[mt][nt], 0, 0, 0);
        __syncthreads();
    }

    float bv[4];
    if (HAS_BIAS) {
        #pragma unroll
        for (int nt = 0; nt < 4; ++nt) bv[nt] = bias[nbase + nt * 16 + lc];
    }
    #pragma unroll
    for (int mt = 0; mt < 2; ++mt)
        #pragma unroll
        for (int nt = 0; nt < 4; ++nt)
            #pragma unroll
            for (int rg = 0; rg < 4; ++rg) {
                int row = mbase + wave * 32 + mt * 16 + q * 4 + rg;
                int col = nbase + nt * 16 + lc;
                float v = acc[mt][nt][rg];
                if (HAS_BIAS) v += bv[nt];
                if (HAS_ADD) v += add[(size_t)row * CH + col];
                if (RELU) v = fmaxf(v, 0.0f);
                out[(size_t)row * CH + col] = v;
            }
}

// ---------------- pairwise-distance via split-bf16 MFMA + per-(row,128-col-slice) top-3 ----
// 128x128 tile, 4 waves in 2x2. BK=32. XOR-swizzled LDS (conflict-free frag reads).
// dot = aH*bH + aH*bM + aM*bH + aM*bM + aH*bL + aL*bH  (f32 acc, err ~2^-32 rel)
__global__ __launch_bounds__(256, 2) void dist_top3_mfma(
    const unsigned short* __restrict__ pa, const unsigned short* __restrict__ pb,
    const unsigned short* __restrict__ pc, const float* __restrict__ sq,
    u64* __restrict__ part)
{
    __shared__ short sA[3][128 * 32];
    __shared__ short sB[3][128 * 32];
    __shared__ u64 xbuf[128][3];

    int tid = threadIdx.x;
    int wave = tid >> 6, lane = tid & 63;
    int wi = wave >> 1, wj = wave & 1;
    int lc = lane & 15, q = lane >> 4;
    int jt = blockIdx.x;
    int ibase = blockIdx.y * 128, jbase = jt * 128;

    f32x4 acc[4][4];
    #pragma unroll
    for (int mt = 0; mt < 4; ++mt)
        #pragma unroll
        for (int nt = 0; nt < 4; ++nt)
            acc[mt][nt] = (f32x4){0.f, 0.f, 0.f, 0.f};

    int srow = lane >> 2;
    int skq  = ((lane & 3) ^ ((lane >> 3) & 3)) * 8;  // XOR-swizzled global 16B slot

    const unsigned short* gsrc[12];
    short* ldst[12];
    {
        const unsigned short* comp[3] = {pa, pb, pc};
        #pragma unroll
        for (int c = 0; c < 3; ++c)
            #pragma unroll
            for (int ch = 0; ch < 2; ++ch) {
                int r0 = (wave * 2 + ch) * 16;
                int n = (c * 2 + ch) * 2;
                gsrc[n + 0] = comp[c] + (size_t)(ibase + r0 + srow) * CH + skq;
                ldst[n + 0] = &sA[c][r0 * 32];
                gsrc[n + 1] = comp[c] + (size_t)(jbase + r0 + srow) * CH + skq;
                ldst[n + 1] = &sB[c][r0 * 32];
            }
    }
    int cq = (q ^ ((lc >> 1) & 3)) * 8;               // swizzled LDS slot for frag reads

    for (int kk = 0; kk < CH; kk += 32) {
        #pragma unroll
        for (int t = 0; t < 12; ++t) { gl_lds16(gsrc[t], ldst[t]); gsrc[t] += 32; }
        __syncthreads();

        s16x8 aH[4], bH[4], aM[4], bM[4], aL[4], bL[4];
        #pragma unroll
        for (int mt = 0; mt < 4; ++mt)
            aH[mt] = *(const s16x8*)&sA[0][(wi * 64 + mt * 16 + lc) * 32 + cq];
        #pragma unroll
        for (int nt = 0; nt < 4; ++nt)
            bH[nt] = *(const s16x8*)&sB[0][(wj * 64 + nt * 16 + lc) * 32 + cq];
        #pragma unroll
        for (int mt = 0; mt < 4; ++mt)
            #pragma unroll
            for (int nt = 0; nt < 4; ++nt)
                acc[mt][nt] = __builtin_amdgcn_mfma_f32_16x16x32_bf16(aH[mt], bH[nt], acc[mt][nt], 0, 0, 0);

        #pragma unroll
        for (int nt = 0; nt < 4; ++nt)
            bM[nt] = *(const s16x8*)&sB[1][(wj * 64 + nt * 16 + lc) * 32 + cq];
        #pragma unroll
        for (int mt = 0; mt < 4; ++mt)
            #pragma unroll
            for (int nt = 0; nt < 4; ++nt)
                acc[mt][nt] = __builtin_amdgcn_mfma_f32_16x16x32_bf16(aH[mt], bM[nt], acc[mt][nt], 0, 0, 0);

        #pragma unroll
        for (int mt = 0; mt < 4; ++mt)
            aM[mt] = *(const s16x8*)&sA[1][(wi * 64 + mt * 16 + lc) * 32 + cq];
        #pragma unroll
        for (int mt = 0; mt < 4; ++mt)
            #pragma unroll
            for (int nt = 0; nt < 4; ++nt)
                acc[mt][nt] = __builtin_amdgcn_mfma_f32_16x16x32_bf16(aM[mt], bH[nt], acc[mt][nt], 0, 0, 0);
        #pragma unroll
        for (int mt = 0; mt < 4; ++mt)
            #pragma unroll
            for (int nt = 0; nt < 4; ++nt)
                acc[mt][nt] = __builtin_amdgcn_mfma_f32_16x16x32_bf16(aM[mt], bM[nt], acc[mt][nt], 0, 0, 0);

        #pragma unroll
        for (int nt = 0; nt < 4; ++nt)
            bL[nt] = *(const s16x8*)&sB[2][(wj * 64 + nt * 16 + lc) * 32 + cq];
        #pragma unroll
        for (int mt = 0; mt < 4; ++mt)
            #pragma unroll
            for (int nt = 0; nt < 4; ++nt)
                acc[mt][nt] = __builtin_amdgcn_mfma_f32_16x16x32_bf16(aH[mt], bL[nt], acc[mt][nt], 0, 0, 0);

        #pragma unroll
        for (int mt = 0; mt < 4; ++mt)
            aL[mt] = *(const s16x8*)&sA[2][(wi * 64 + mt * 16 + lc) * 32 + cq];
        #pragma unroll
        for (int mt = 0; mt < 4; ++mt)
            #pragma unroll
            for (int nt = 0; nt < 4; ++nt)
                acc[mt][nt] = __builtin_amdgcn_mfma_f32_16x16x32_bf16(aL[mt], bH[nt], acc[mt][nt], 0, 0, 0);

        __syncthreads();
    }

    // ---- epilogue: D = (sq_i + sq_j) - 2*dot, per-row top3, merge across lanes/waves ----
    float sqjv[4];
    #pragma unroll
    for (int nt = 0; nt < 4; ++nt) sqjv[nt] = sq[jbase + wj * 64 + nt * 16 + lc];

    #pragma unroll
    for (int mt = 0; mt < 4; ++mt) {
        u64 trip[4][3];
        #pragma unroll
        for (int rg = 0; rg < 4; ++rg) {
            int rl = mt * 16 + q * 4 + rg;
            float sqi = sq[ibase + wi * 64 + rl];
            u64 t0 = ~0ULL, t1 = ~0ULL, t2 = ~0ULL;
            #pragma unroll
            for (int nt = 0; nt < 4; ++nt) {
                float dv = (sqi + sqjv[nt]) - 2.0f * acc[mt][nt][rg];
                unsigned col = (unsigned)(jbase + wj * 64 + nt * 16 + lc);
                ins3(t0, t1, t2, pack_di(dv, col));
            }
            #pragma unroll
            for (int m = 1; m < 16; m <<= 1) {
                u64 b0 = __shfl_xor(t0, m, 64);
                u64 b1 = __shfl_xor(t1, m, 64);
                u64 b2 = __shfl_xor(t2, m, 64);
                merge3(t0, t1, t2, b0, b1, b2);
            }
            trip[rg][0] = t0; trip[rg][1] = t1; trip[rg][2] = t2;
        }
        int rbase = wi * 64 + mt * 16 + q * 4;
        if (wj == 1 && lc == 0) {
            #pragma unroll
            for (int rg = 0; rg < 4; ++rg) {
                xbuf[rbase + rg][0] = trip[rg][0];
                xbuf[rbase + rg][1] = trip[rg][1];
                xbuf[rbase + rg][2] = trip[rg][2];
            }
        }
        __syncthreads();
        if (wj == 0 && lc == 0) {
            #pragma unroll
            for (int rg = 0; rg < 4; ++rg) {
                u64 t0 = trip[rg][0], t1 = trip[rg][1], t2 = trip[rg][2];
                merge3(t0, t1, t2, xbuf[rbase + rg][0], xbuf[rbase + rg][1], xbuf[rbase + rg][2]);
                u64* dp = part + ((size_t)(ibase + rbase + rg) * 64 + jt) * 3;
                dp[0] = t0; dp[1] = t1; dp[2] = t2;
            }
        }
        __syncthreads();
    }
}

// ---------------- merge 64 partial top-3s per row, gather+sum h rows ----------------
__global__ __launch_bounds__(256) void merge_gather(
    const u64* __restrict__ part, const float* __restrict__ h, float* __restrict__ agg)
{
    int wave = threadIdx.x >> 6, lane = threadIdx.x & 63;
    int row = blockIdx.x * 4 + wave;
    const u64* pr = part + (size_t)row * 192 + lane * 3;
    u64 t0 = pr[0], t1 = pr[1], t2 = pr[2];
    #pragma unroll
    for (int m = 32; m; m >>= 1) {
        u64 b0 = __shfl_xor(t0, m, 64);
        u64 b1 = __shfl_xor(t1, m, 64);
        u64 b2 = __shfl_xor(t2, m, 64);
        merge3(t0, t1, t2, b0, b1, b2);
    }
    int i0 = (int)(t0 & 0xffffffffu);
    int i1 = (int)(t1 & 0xffffffffu);
    int i2 = (int)(t2 & 0xffffffffu);
    const float4* h4 = (const float4*)h;
    float4 a = h4[(size_t)i0 * 64 + lane];
    float4 b = h4[(size_t)i1 * 64 + lane];
    float4 c = h4[(size_t)i2 * 64 + lane];
    float4 o;
    o.x = (a.x + b.x) + c.x;
    o.y = (a.y + b.y) + c.y;
    o.z = (a.z + b.z) + c.z;
    o.w = (a.w + b.w) + c.w;
    ((float4*)agg)[(size_t)row * 64 + lane] = o;
}

// ---------------- out = x1 @ W2^T + b2  (N=2) ----------------
__global__ __launch_bounds__(256) void linear2_kernel(
    const float* __restrict__ x1, const float* __restrict__ W2,
    const float* __restrict__ b2, float* __restrict__ out)
{
    int wave = threadIdx.x >> 6, lane = threadIdx.x & 63;
    int row = blockIdx.x * 4 + wave;
    float4 v = ((const float4*)(x1 + (size_t)row * CH))[lane];
    float4 w0 = ((const float4*)W2)[lane];
    float4 w1 = ((const float4*)W2)[64 + lane];
    float d0 = (v.x * w0.x + v.y * w0.y) + (v.z * w0.z + v.w * w0.w);
    float d1 = (v.x * w1.x + v.y * w1.y) + (v.z * w1.z + v.w * w1.w);
    #pragma unroll
    for (int off = 32; off; off >>= 1) {
        d0 += __shfl_xor(d0, off, 64);
        d1 += __shfl_xor(d1, off, 64);
    }
    if (lane == 0) {
        out[(size_t)row * 2 + 0] = d0 + b2[0];
        out[(size_t)row * 2 + 1] = d1 + b2[1];
    }
}

extern "C" void kernel_launch(void* const* d_in, const int* in_sizes, int n_in,
                              void* d_out, int out_size, void* d_ws, size_t ws_size,
                              hipStream_t stream) {
    const float* x    = (const float*)d_in[0];
    const float* W1   = (const float*)d_in[1];
    const float* b1   = (const float*)d_in[2];
    const float* Wrel = (const float*)d_in[3];
    const float* brel = (const float*)d_in[4];
    const float* Wroot= (const float*)d_in[5];
    const float* W2   = (const float*)d_in[6];
    const float* b2   = (const float*)d_in[7];

    float* outp = (float*)d_out;            // [8192*2] first
    float* x1   = outp + (size_t)NN * 2;    // [8192*256] second output

    char* ws = (char*)d_ws;
    float* p  = (float*)ws;                                  // 8 MB (reused as agg)
    float* h  = (float*)(ws + (8ull << 20));                 // 8 MB
    float* sq = (float*)(ws + (16ull << 20));                // 64 KB pad
    char* base = ws + (16ull << 20) + (64ull << 10);
    unsigned short* pa = (unsigned short*)(base);                   // 4 MB
    unsigned short* pb = (unsigned short*)(base + (4ull  << 20));   // 4 MB
    unsigned short* pc = (unsigned short*)(base + (8ull  << 20));   // 4 MB
    u64* part          = (u64*)          (base + (12ull << 20));    // 12 MB
    unsigned short* xh = (unsigned short*)(base + (24ull << 20));   // 4 MB (reused as h-split hi)
    unsigned short* xm = (unsigned short*)(base + (28ull << 20));   // 4 MB (reused as h-split mid)
    char* wsp = base + (32ull << 20);
    unsigned short* W1h   = (unsigned short*)(wsp);
    unsigned short* W1m   = (unsigned short*)(wsp + 131072);
    unsigned short* Wrelh = (unsigned short*)(wsp + 2 * 131072);
    unsigned short* Wrelm = (unsigned short*)(wsp + 3 * 131072);
    unsigned short* Wrth  = (unsigned short*)(wsp + 4 * 131072);
    unsigned short* Wrtm  = (unsigned short*)(wsp + 5 * 131072);
    float* agg = p;                       // p dead after split3
    float* t   = (float*)pa;              // pa+pb (8 MB) dead after dist
    unsigned short* gh = (unsigned short*)pc;     // pc dead after dist
    unsigned short* gm = (unsigned short*)part;   // part dead after merge_gather

    // 1. softmax + sq
    softmax_kernel<<<NN / 4, 256, 0, stream>>>(x, p, sq);
    // 2. split p -> bf16 hi/mid/lo (for dist); split x, weights -> hi/mid (for GEMMs)
    split3_kernel<<<(NN * CH) / 1024, 256, 0, stream>>>(p, pa, pb, pc);
    split2_kernel<<<(NN * CH) / 1024, 256, 0, stream>>>(x, xh, xm);
    splitw_kernel<<<192, 256, 0, stream>>>(W1, Wrel, Wroot, W1h, W1m, Wrelh, Wrelm, Wrth, Wrtm);
    // 3. h = relu(x @ W1^T + b1)
    gemm_mfma<true, true, false><<<dim3(NN / 128, CH / 64), 256, 0, stream>>>(
        xh, xm, W1h, W1m, b1, nullptr, h);
    // 4. pairwise distances via split-bf16 MFMA + per-slice top3
    dist_top3_mfma<<<dim3(64, 64), 256, 0, stream>>>(pa, pb, pc, sq, part);
    // 5. global top3 merge + gather-sum of h rows
    merge_gather<<<NN / 4, 256, 0, stream>>>(part, h, agg);
    // 6. splits of h and agg (xh/xm reused for h's split)
    split2_kernel<<<(NN * CH) / 1024, 256, 0, stream>>>(h, xh, xm);
    split2_kernel<<<(NN * CH) / 1024, 256, 0, stream>>>(agg, gh, gm);
    // 7. t = agg @ Wrel^T + brel
    gemm_mfma<false, true, false><<<dim3(NN / 128, CH / 64), 256, 0, stream>>>(
        gh, gm, Wrelh, Wrelm, brel, nullptr, t);
    // 8. x1 = relu(h @ Wroot^T + t)
    gemm_mfma<true, false, true><<<dim3(NN / 128, CH / 64), 256, 0, stream>>>(
        xh, xm, Wrth, Wrtm, nullptr, t, x1);
    // 9. out = x1 @ W2^T + b2
    linear2_kernel<<<NN / 4, 256, 0, stream>>>(x1, W2, b2, outp);
}